// Round 1
// baseline (1039.170 us; speedup 1.0000x reference)
//
#include <hip/hip_runtime.h>
#include <hip/hip_bf16.h>

// OnlineLayer: res-LN + conv + per-partition graph aggregation (the big GEMM vs
// A: 3x8192x8192 fp32 = 805MB, streamed once -> HBM-bound ~128us floor) + FIFO
// step + LN/ReLU epilogue.
//
// ws layout (bytes):
//   [0, 1572864)          h bf16   (96 x 8192)
//   [1572864, 2621440)    y/agg f32 (32 x 8192)   (memset 0; k2 atomicAdd; k3 rewrites as agg)
//   [2621440, 3670016)    res f32  (32 x 8192)
//   [3670016, 3670032)    stats f32[4]: res_sum, res_sq, agg_sum, agg_sq (memset 0)

#define PP 3
#define CIN 64
#define COUT 32
#define VV 8192
#define EPSL 1e-5f

typedef short v8s __attribute__((ext_vector_type(8)));
typedef float v4f __attribute__((ext_vector_type(4)));

// ---------------- block reduce (2 values) + atomic ----------------
__device__ __forceinline__ void block_reduce2_atomic(float s1, float s2,
                                                     float* d1, float* d2) {
  #pragma unroll
  for (int off = 32; off > 0; off >>= 1) {
    s1 += __shfl_down(s1, off, 64);
    s2 += __shfl_down(s2, off, 64);
  }
  __shared__ float r1[4], r2[4];
  int lane = threadIdx.x & 63, wv = threadIdx.x >> 6;
  if (lane == 0) { r1[wv] = s1; r2[wv] = s2; }
  __syncthreads();
  if (threadIdx.x == 0) {
    atomicAdd(d1, r1[0] + r1[1] + r1[2] + r1[3]);
    atomicAdd(d2, r2[0] + r2[1] + r2[2] + r2[3]);
  }
}

// ---------------- K1: convs (h bf16, res f32) + res stats ----------------
// grid (32, 4), block 256. og 0..2 -> h rows og*32..og*32+31 ; og 3 -> res.
__global__ __launch_bounds__(256) void k1_conv(
    const float* __restrict__ x, const float* __restrict__ conv_w,
    const float* __restrict__ conv_b, const float* __restrict__ res_w,
    __hip_bfloat16* __restrict__ h, float* __restrict__ res,
    float* __restrict__ stats) {
  int v = blockIdx.x * 256 + threadIdx.x;
  int og = blockIdx.y;
  float xr[CIN];
  #pragma unroll
  for (int c = 0; c < CIN; ++c) xr[c] = x[c * VV + v];

  if (og < 3) {
    for (int i = 0; i < 32; ++i) {
      int o = og * 32 + i;
      float acc = conv_b[o];
      #pragma unroll
      for (int c = 0; c < CIN; ++c) acc = fmaf(conv_w[o * CIN + c], xr[c], acc);
      h[o * VV + v] = __float2bfloat16(acc);
    }
  } else {
    float s1 = 0.f, s2 = 0.f;
    for (int o = 0; o < COUT; ++o) {
      float acc = 0.f;
      #pragma unroll
      for (int c = 0; c < CIN; ++c) acc = fmaf(res_w[o * CIN + c], xr[c], acc);
      res[o * VV + v] = acc;
      s1 += acc; s2 += acc * acc;
    }
    block_reduce2_atomic(s1, s2, &stats[0], &stats[1]);
  }
}

// ---------------- K2: y += h @ A  (the HBM-bound GEMM) ----------------
// M=32 (c), N tile 128 (w), split-K 16, K-chunk 32.
// LDS chunk layout: 16 row-pairs; pair pr = rows (2pr, 2pr+1), 1024B data +
// 16B pad (stride 1040B = 260 dwords) -> 2-way-bank (free) frag reads, and
// global_load_lds's lane-contiguous dest constraint is satisfied per pair.
#define TN 128
#define KC 32
#define CHUNKS 48
#define PAIR_DW 260
#define PAIR_BYTES 1040
#define BUF_BYTES (16 * PAIR_BYTES)

__global__ __launch_bounds__(256) void k2_gemm(
    const float* __restrict__ A, const __hip_bfloat16* __restrict__ h,
    float* __restrict__ y) {
  __shared__ char lds_raw[2][BUF_BYTES];
  const int tid = threadIdx.x;
  const int wv = tid >> 6, lane = tid & 63;
  const int quad = lane >> 4, l15 = lane & 15;
  const int wbase = blockIdx.x * TN;
  const int kbase = blockIdx.y * (KC * CHUNKS);
  const int srow = lane >> 5;          // row within pair
  const int scol = (lane & 31) * 4;    // float col within tile

  v4f acc[2][2] = {};

  auto stage = [&](int buf, int chunk) {
    int k0 = kbase + chunk * KC;
    int p = k0 >> 13, v0 = k0 & (VV - 1);
    const float* Ap = A + ((size_t)p << 26);
    for (int pr = wv; pr < 16; pr += 4) {
      const float* gp = Ap + (size_t)(v0 + 2 * pr + srow) * VV + wbase + scol;
      void* lp = (void*)&lds_raw[buf][pr * PAIR_BYTES];
      __builtin_amdgcn_global_load_lds(
          (const __attribute__((address_space(1))) void*)gp,
          (__attribute__((address_space(3))) void*)lp, 16, 0, 0);
    }
  };

  stage(0, 0);
  __syncthreads();

  for (int c = 0; c < CHUNKS; ++c) {
    int cur = c & 1;
    if (c + 1 < CHUNKS) stage(cur ^ 1, c + 1);  // async, in flight over compute

    int kk = kbase + c * KC;
    int p = kk >> 13, v0 = kk & (VV - 1);
    const float* lf = (const float*)lds_raw[cur];

    // A-frags straight from global h (bf16, L2-resident): A[m=l15][k=quad*8+j]
    const __hip_bfloat16* hp =
        h + (size_t)(p * COUT + l15) * VV + v0 + quad * 8;
    v8s afrag0 = *(const v8s*)hp;
    v8s afrag1 = *(const v8s*)(hp + 16 * VV);

    #pragma unroll
    for (int nt = 0; nt < 2; ++nt) {
      int wl = wv * 32 + nt * 16 + l15;
      union { unsigned u[4]; v8s s; } bf;
      #pragma unroll
      for (int t = 0; t < 4; ++t) {
        int pr = quad * 4 + t;  // k elems 2t,2t+1 -> rows (quad*8+2t, +1)
        float f0 = lf[pr * PAIR_DW + wl];
        float f1 = lf[pr * PAIR_DW + 128 + wl];
        // pack hi16(f1):hi16(f0)  (bf16 truncation)
        bf.u[t] = __builtin_amdgcn_perm(__float_as_uint(f1),
                                        __float_as_uint(f0), 0x07060302u);
      }
      acc[0][nt] = __builtin_amdgcn_mfma_f32_16x16x32_bf16(afrag0, bf.s, acc[0][nt], 0, 0, 0);
      acc[1][nt] = __builtin_amdgcn_mfma_f32_16x16x32_bf16(afrag1, bf.s, acc[1][nt], 0, 0, 0);
    }
    __syncthreads();  // drains next-chunk loads; guards buffer reuse
  }

  // C/D: col(w)=lane&15, row(c)=(lane>>4)*4+reg  [m89/m91]
  #pragma unroll
  for (int mt = 0; mt < 2; ++mt)
    #pragma unroll
    for (int nt = 0; nt < 2; ++nt)
      #pragma unroll
      for (int r = 0; r < 4; ++r) {
        int crow = mt * 16 + quad * 4 + r;
        int w = wbase + wv * 32 + nt * 16 + l15;
        atomicAdd(&y[(size_t)crow * VV + w], acc[mt][nt][r]);
      }
}

// ---------------- K3: agg = acc + y - fifo (in place over y) + stats ----------------
__global__ __launch_bounds__(256) void k3_agg(
    const float* __restrict__ acc_slot, const float* __restrict__ fifo,
    float* __restrict__ y, float* __restrict__ stats) {
  int i = blockIdx.x * 256 + threadIdx.x;  // float4 index (65536 total)
  float4 yv = ((const float4*)y)[i];
  float4 av = ((const float4*)acc_slot)[i];
  float4 fv = ((const float4*)fifo)[i];
  float4 g;
  g.x = av.x + yv.x - fv.x;
  g.y = av.y + yv.y - fv.y;
  g.z = av.z + yv.z - fv.z;
  g.w = av.w + yv.w - fv.w;
  ((float4*)y)[i] = g;
  float s1 = g.x + g.y + g.z + g.w;
  float s2 = g.x * g.x + g.y * g.y + g.z * g.z + g.w * g.w;
  block_reduce2_atomic(s1, s2, &stats[2], &stats[3]);
}

// ---------------- K4: out = relu(relu(LN(agg)) + LN(res)) ----------------
__global__ __launch_bounds__(256) void k4_final(
    const float* __restrict__ agg, const float* __restrict__ res,
    const float* __restrict__ ln_w, const float* __restrict__ ln_b,
    const float* __restrict__ res_ln_w, const float* __restrict__ res_ln_b,
    const float* __restrict__ stats, float* __restrict__ out) {
  const float inv_n = 1.0f / (COUT * VV);
  float mr = stats[0] * inv_n;
  float vr = stats[1] * inv_n - mr * mr;
  float rsr = rsqrtf(vr + EPSL);
  float ma = stats[2] * inv_n;
  float va = stats[3] * inv_n - ma * ma;
  float rsa = rsqrtf(va + EPSL);

  int i = blockIdx.x * 256 + threadIdx.x;
  float4 g = ((const float4*)agg)[i];
  float4 r = ((const float4*)res)[i];
  float4 w1 = ((const float4*)ln_w)[i], b1 = ((const float4*)ln_b)[i];
  float4 w2 = ((const float4*)res_ln_w)[i], b2 = ((const float4*)res_ln_b)[i];
  float4 o;
  o.x = fmaxf(fmaxf((g.x - ma) * rsa * w1.x + b1.x, 0.f) + (r.x - mr) * rsr * w2.x + b2.x, 0.f);
  o.y = fmaxf(fmaxf((g.y - ma) * rsa * w1.y + b1.y, 0.f) + (r.y - mr) * rsr * w2.y + b2.y, 0.f);
  o.z = fmaxf(fmaxf((g.z - ma) * rsa * w1.z + b1.z, 0.f) + (r.z - mr) * rsr * w2.z + b2.z, 0.f);
  o.w = fmaxf(fmaxf((g.w - ma) * rsa * w1.w + b1.w, 0.f) + (r.w - mr) * rsr * w2.w + b2.w, 0.f);
  ((float4*)out)[i] = o;
}

extern "C" void kernel_launch(void* const* d_in, const int* in_sizes, int n_in,
                              void* d_out, int out_size, void* d_ws, size_t ws_size,
                              hipStream_t stream) {
  const float* x        = (const float*)d_in[0];
  const float* A        = (const float*)d_in[1];
  const float* conv_w   = (const float*)d_in[2];
  const float* conv_b   = (const float*)d_in[3];
  const float* fifo     = (const float*)d_in[4];
  const float* acc_slot = (const float*)d_in[5];
  const float* ln_w     = (const float*)d_in[6];
  const float* ln_b     = (const float*)d_in[7];
  const float* res_w    = (const float*)d_in[8];
  const float* res_ln_w = (const float*)d_in[9];
  const float* res_ln_b = (const float*)d_in[10];
  float* out = (float*)d_out;

  char* ws = (char*)d_ws;
  __hip_bfloat16* h = (__hip_bfloat16*)ws;
  float* y     = (float*)(ws + 1572864);
  float* res   = (float*)(ws + 1572864 + 1048576);
  float* stats = (float*)(ws + 1572864 + 2097152);

  hipMemsetAsync(y, 0, COUT * VV * sizeof(float), stream);
  hipMemsetAsync(stats, 0, 4 * sizeof(float), stream);

  k1_conv<<<dim3(32, 4), 256, 0, stream>>>(x, conv_w, conv_b, res_w, h, res, stats);
  k2_gemm<<<dim3(VV / TN, 16), 256, 0, stream>>>(A, h, y);
  k3_agg<<<256, 256, 0, stream>>>(acc_slot, fifo, y, stats);
  k4_final<<<256, 256, 0, stream>>>(y, res, ln_w, ln_b, res_ln_w, res_ln_b, stats, out);
}